// Round 8
// baseline (137.979 us; speedup 1.0000x reference)
//
#include <hip/hip_runtime.h>
#include <cstdint>

typedef unsigned long long u64;
typedef _Float16 half8 __attribute__((ext_vector_type(8)));
typedef float f32x4 __attribute__((ext_vector_type(4)));

static constexpr int Dd = 128;
static constexpr float EPSf = 1e-6f;
static constexpr float MARGINf = 1.0f;
static constexpr float BIGf = 3.0e38f;

// Monotonic map fp32 -> u32 (total order matching float compare).
__device__ __forceinline__ unsigned fkey(float f) {
  unsigned b = __float_as_uint(f);
  return (b & 0x80000000u) ? ~b : (b | 0x80000000u);
}

// Block = 16 rows. Coalesced packed-fragment writes:
// half idx = ((T*4+ks)*64 + lg*16 + r15)*8 + h ; T=row>>4, k=ks*32+lg*8+h.
__global__ __launch_bounds__(256) void k_prep(const float* __restrict__ E,
                                              _Float16* __restrict__ Ehp,
                                              float* __restrict__ normf) {
  __shared__ float part[4][16];
  const int t = threadIdx.x;
  const int b = blockIdx.x;  // rows [b*16, b*16+16)
  const int ks = t >> 6, r15 = t & 15;
  const int lg = (t >> 4) & 3;
  const float* src = E + (size_t)(b * 16 + r15) * Dd + ks * 32 + lg * 8;
  float4 v0 = *(const float4*)src;
  float4 v1 = *(const float4*)(src + 4);
  half8 hv;
  hv[0] = (_Float16)v0.x; hv[1] = (_Float16)v0.y;
  hv[2] = (_Float16)v0.z; hv[3] = (_Float16)v0.w;
  hv[4] = (_Float16)v1.x; hv[5] = (_Float16)v1.y;
  hv[6] = (_Float16)v1.z; hv[7] = (_Float16)v1.w;
  *(half8*)((char*)Ehp + (size_t)b * 4096 + t * 16) = hv;  // fully coalesced
  float s = v0.x * v0.x + v0.y * v0.y + v0.z * v0.z + v0.w * v0.w +
            v1.x * v1.x + v1.y * v1.y + v1.z * v1.z + v1.w * v1.w;
  s += __shfl_xor(s, 16);
  s += __shfl_xor(s, 32);
  if (((t >> 4) & 3) == 0) part[ks][r15] = s;
  __syncthreads();
  if (t < 16) normf[b * 16 + t] = part[0][t] + part[1][t] + part[2][t] + part[3][t];
}

// Exact hardest-positive per row: one block per label group (~8 members).
__global__ __launch_bounds__(256) void k_pos(const float* __restrict__ E,
                                             const int* __restrict__ lab,
                                             int* __restrict__ posIdx) {
  __shared__ int cnt;
  __shared__ int mlist[64];
  __shared__ float X[64][129];
  const int t = threadIdx.x;
  const int lbl = blockIdx.x;
  if (t == 0) cnt = 0;
  __syncthreads();
  for (int r = t; r < 8192; r += 256)
    if (lab[r] == lbl) {
      int p = atomicAdd(&cnt, 1);
      if (p < 64) mlist[p] = r;
    }
  __syncthreads();
  const int c = min(cnt, 64);
  for (int mb = 0; mb < c; mb += 2) {
    int m = mb + (t >> 7);
    if (m < c) X[m][t & 127] = E[(size_t)mlist[m] * Dd + (t & 127)];
  }
  __syncthreads();
  const int w = t >> 6, l = t & 63;
  for (int mi = w; mi < c; mi += 4) {
    int gi = mlist[mi];
    u64 pk = 0ull;
    if (l < c) {
      float s = 0.f;
      for (int k = 0; k < 128; ++k) {
        float d = X[mi][k] - X[l][k];
        s = fmaf(d, d, s);
      }
      pk = ((u64)fkey(s) << 32) | (u64)(0xFFFFFFFFu - (unsigned)mlist[l]);
    }
    #pragma unroll
    for (int off = 1; off < 64; off <<= 1) {
      u64 o = __shfl_xor(pk, off);
      pk = pk > o ? pk : o;
    }
    if (l == 0)
      posIdx[gi] = ((unsigned)(pk >> 32) > 0x80000000u)
                       ? (int)(0xFFFFFFFFu - (unsigned)(pk & 0xFFFFFFFFull))
                       : gi;
  }
}

// Hardest-negative: block = 256 i-rows (4 waves x 64, frags in regs),
// strip = 512 j streamed as 4 LDS double-buffered 128-row tiles.
// Staging via plain vector loads -> registers -> ds_write (L2-cacheable;
// global_load_lds showed zero L2 absorption on this platform: R2 8.7MB vs
// R5-R7 118MB FETCH A/B). Loads for tile t+1 issued before compute of t.
__global__ __launch_bounds__(256, 2) void k_neg(const _Float16* __restrict__ Ehp,
                                                const float* __restrict__ normf,
                                                float* __restrict__ negPart) {
  __shared__ __align__(16) char jbuf[2][32768];

  const int t = threadIdx.x;
  const int w = t >> 6, l = t & 63;
  const int lane15 = l & 15, lg = l >> 4;
  const int gi0 = blockIdx.x * 256 + w * 64;  // wave i-base (32 panels)
  const int jb = blockIdx.y * 512;            // strip j-base (16 strips)
  const char* jsrc = (const char*)Ehp + (size_t)(jb >> 4) * 4096;
  const char* wsrc = jsrc + w * 8192;  // this wave's 8KB slice of each tile

  // i-side fragments (64 VGPR), coalesced from packed layout
  half8 bf[4][4];
  #pragma unroll
  for (int it = 0; it < 4; ++it)
    #pragma unroll
    for (int ks = 0; ks < 4; ++ks)
      bf[it][ks] = *(const half8*)(Ehp + ((size_t)((gi0 >> 4) + it) * 4 + ks) * 512 +
                                   (size_t)l * 8);

  // prologue: tile 0 -> regs -> LDS
  half8 sreg[8];
  #pragma unroll
  for (int q = 0; q < 8; ++q)
    sreg[q] = *(const half8*)(wsrc + q * 1024 + l * 16);
  #pragma unroll
  for (int q = 0; q < 8; ++q)
    *(half8*)(&jbuf[0][0] + w * 8192 + q * 1024 + l * 16) = sreg[q];
  __syncthreads();

  float bn[4] = {BIGf, BIGf, BIGf, BIGf};

  #pragma unroll
  for (int tt = 0; tt < 4; ++tt) {
    const int cur = tt & 1;
    if (tt < 3) {  // issue next tile's loads; latency hides under MFMA below
      const char* s = wsrc + (size_t)(tt + 1) * 32768;
      #pragma unroll
      for (int q = 0; q < 8; ++q)
        sreg[q] = *(const half8*)(s + q * 1024 + l * 16);
    }

    #pragma unroll
    for (int jt = 0; jt < 8; ++jt) {
      half8 af[4];
      #pragma unroll
      for (int ks = 0; ks < 4; ++ks)
        af[ks] = *(const half8*)(&jbuf[cur][0] + (jt * 4 + ks) * 1024 + l * 16);
      f32x4 ac[4];
      #pragma unroll
      for (int it = 0; it < 4; ++it) ac[it] = (f32x4){0.f, 0.f, 0.f, 0.f};
      __builtin_amdgcn_s_setprio(1);
      #pragma unroll
      for (int ks = 0; ks < 4; ++ks)
        #pragma unroll
        for (int it = 0; it < 4; ++it)
          ac[it] = __builtin_amdgcn_mfma_f32_16x16x32_f16(af[ks], bf[it][ks], ac[it], 0, 0, 0);
      __builtin_amdgcn_s_setprio(0);

      const float4 nj = *(const float4*)(normf + jb + tt * 128 + jt * 16 + lg * 4);
      const unsigned b9 = (unsigned)(tt * 128 + jt * 16 + lg * 4);
      #pragma unroll
      for (int it = 0; it < 4; ++it) {
        // d'' = nj - 2g (row-constant ni dropped: order-invariant)
        float c0 = fmaf(ac[it][0], -2.0f, nj.x);
        float c1 = fmaf(ac[it][1], -2.0f, nj.y);
        float c2 = fmaf(ac[it][2], -2.0f, nj.z);
        float c3 = fmaf(ac[it][3], -2.0f, nj.w);
        // stuff 9-bit strip-local j into the mantissa
        c0 = __uint_as_float((__float_as_uint(c0) & 0xFFFFFE00u) | (b9 + 0u));
        c1 = __uint_as_float((__float_as_uint(c1) & 0xFFFFFE00u) | (b9 + 1u));
        c2 = __uint_as_float((__float_as_uint(c2) & 0xFFFFFE00u) | (b9 + 2u));
        c3 = __uint_as_float((__float_as_uint(c3) & 0xFFFFFE00u) | (b9 + 3u));
        if (jb + tt * 128 + jt * 16 == gi0 + it * 16) {  // wave-uniform: diag tile
          int rr = lane15 - lg * 4;
          if (rr == 0) c0 = BIGf;
          else if (rr == 1) c1 = BIGf;
          else if (rr == 2) c2 = BIGf;
          else if (rr == 3) c3 = BIGf;
        }
        bn[it] = fminf(bn[it], fminf(fminf(c0, c1), fminf(c2, c3)));
      }
    }
    __syncthreads();  // all waves done reading jbuf[cur]
    if (tt < 3) {
      #pragma unroll
      for (int q = 0; q < 8; ++q)
        *(half8*)(&jbuf[cur ^ 1][0] + w * 8192 + q * 1024 + l * 16) = sreg[q];
    }
    __syncthreads();  // next tile visible to all waves
  }

  // merge the 4 lg-lanes (same i, disjoint j), write per-strip partial
  #pragma unroll
  for (int it = 0; it < 4; ++it) {
    float v = bn[it];
    v = fminf(v, __shfl_xor(v, 16));
    v = fminf(v, __shfl_xor(v, 32));
    if (lg == 0)
      negPart[(size_t)blockIdx.y * 8192 + gi0 + it * 16 + lane15] = v;
  }
}

// One wave per row: merge 16 strip partials, exact fp32 triplet term.
__global__ __launch_bounds__(256) void k_final(const float* __restrict__ E,
                                               const int* __restrict__ posIdx,
                                               const float* __restrict__ negPart,
                                               float* __restrict__ rowLoss) {
  int i = (blockIdx.x * 256 + threadIdx.x) >> 6;
  int l = threadIdx.x & 63;
  u64 pk = ~0ull;
  if (l < 16) {
    float v = negPart[(size_t)l * 8192 + i];
    unsigned u = __float_as_uint(v);
    pk = ((u64)fkey(v) << 32) | (u64)(unsigned)((l << 9) | (u & 511u));
  }
  #pragma unroll
  for (int off = 1; off < 64; off <<= 1) {
    u64 o = __shfl_xor(pk, off);
    pk = pk < o ? pk : o;
  }
  int jn = (int)(pk & 8191ull);
  int jp = posIdx[i];
  float2 a = *(const float2*)(E + (size_t)i * Dd + l * 2);
  float2 p = *(const float2*)(E + (size_t)jp * Dd + l * 2);
  float2 n = *(const float2*)(E + (size_t)jn * Dd + l * 2);
  float dx = a.x - p.x + EPSf, dy = a.y - p.y + EPSf;
  float sap = dx * dx + dy * dy;
  dx = a.x - n.x + EPSf;
  dy = a.y - n.y + EPSf;
  float san = dx * dx + dy * dy;
  #pragma unroll
  for (int off = 32; off; off >>= 1) {
    sap += __shfl_xor(sap, off);
    san += __shfl_xor(san, off);
  }
  if (l == 0) rowLoss[i] = fmaxf(sqrtf(sap) - sqrtf(san) + MARGINf, 0.0f);
}

// Deterministic tree reduction -> mean.
__global__ __launch_bounds__(256) void k_reduce(const float* __restrict__ rowLoss,
                                                float* __restrict__ out) {
  __shared__ float s[256];
  int t = threadIdx.x;
  float sum = 0.f;
  for (int q = 0; q < 32; ++q) sum += rowLoss[t + 256 * q];
  s[t] = sum;
  __syncthreads();
  for (int off = 128; off; off >>= 1) {
    if (t < off) s[t] += s[t + off];
    __syncthreads();
  }
  if (t == 0) out[0] = s[0] * (1.0f / 8192.0f);
}

extern "C" void kernel_launch(void* const* d_in, const int* in_sizes, int n_in,
                              void* d_out, int out_size, void* d_ws, size_t ws_size,
                              hipStream_t stream) {
  const float* E = (const float*)d_in[0];
  const int* lab = (const int*)d_in[1];
  float* out = (float*)d_out;

  char* wsp = (char*)d_ws;
  float* negPart = (float*)wsp;                     // 16*8192*4 = 512 KB
  int* posIdx = (int*)(wsp + (1024 << 10));         // 32 KB
  float* normf = (float*)(wsp + (1056 << 10));      // 32 KB
  float* rowLoss = (float*)(wsp + (1088 << 10));    // 32 KB
  _Float16* Ehp = (_Float16*)(wsp + (1152 << 10));  // 2 MB packed frags

  k_prep<<<512, 256, 0, stream>>>(E, Ehp, normf);
  k_pos<<<1000, 256, 0, stream>>>(E, lab, posIdx);
  k_neg<<<dim3(32, 16), 256, 0, stream>>>(Ehp, normf, negPart);
  k_final<<<2048, 256, 0, stream>>>(E, posIdx, negPart, rowLoss);
  k_reduce<<<1, 256, 0, stream>>>(rowLoss, out);
}

// Round 9
// 71.529 us; speedup vs baseline: 1.9290x; 1.9290x over previous
//
#include <hip/hip_runtime.h>
#include <cstdint>

typedef unsigned long long u64;
typedef _Float16 half8 __attribute__((ext_vector_type(8)));
typedef float f32x4 __attribute__((ext_vector_type(4)));

static constexpr int Dd = 128;
static constexpr float EPSf = 1e-6f;
static constexpr float MARGINf = 1.0f;
static constexpr float BIGf = 3.0e38f;

// Monotonic map fp32 -> u32 (total order matching float compare).
__device__ __forceinline__ unsigned fkey(float f) {
  unsigned b = __float_as_uint(f);
  return (b & 0x80000000u) ? ~b : (b | 0x80000000u);
}

// One wave per row: fp32 norm (exact), fp16 convert (row-major), negPack init.
__global__ __launch_bounds__(256) void k_prep(const float* __restrict__ E,
                                              _Float16* __restrict__ Eh,
                                              float* __restrict__ normf,
                                              u64* __restrict__ negPack) {
  int row = (blockIdx.x * 256 + threadIdx.x) >> 6;
  int l = threadIdx.x & 63;
  float2 v = *(const float2*)(E + (size_t)row * Dd + l * 2);
  union { _Float16 h[2]; unsigned u; } cv;
  cv.h[0] = (_Float16)v.x;
  cv.h[1] = (_Float16)v.y;
  *(unsigned*)(Eh + (size_t)row * Dd + l * 2) = cv.u;
  float s = v.x * v.x + v.y * v.y;
  #pragma unroll
  for (int off = 32; off; off >>= 1) s += __shfl_xor(s, off);
  if (l == 0) {
    normf[row] = s;
    negPack[row] = ~0ull;
  }
}

// Exact hardest-positive per row: one block per label group (~8 members).
__global__ __launch_bounds__(256) void k_pos(const float* __restrict__ E,
                                             const int* __restrict__ lab,
                                             int* __restrict__ posIdx) {
  __shared__ int cnt;
  __shared__ int mlist[64];
  __shared__ float X[64][129];
  const int t = threadIdx.x;
  const int lbl = blockIdx.x;
  if (t == 0) cnt = 0;
  __syncthreads();
  for (int r = t; r < 8192; r += 256)
    if (lab[r] == lbl) {
      int p = atomicAdd(&cnt, 1);
      if (p < 64) mlist[p] = r;
    }
  __syncthreads();
  const int c = min(cnt, 64);
  for (int mb = 0; mb < c; mb += 2) {
    int m = mb + (t >> 7);
    if (m < c) X[m][t & 127] = E[(size_t)mlist[m] * Dd + (t & 127)];
  }
  __syncthreads();
  const int w = t >> 6, l = t & 63;
  for (int mi = w; mi < c; mi += 4) {
    int gi = mlist[mi];
    u64 pk = 0ull;
    if (l < c) {
      float s = 0.f;
      for (int k = 0; k < 128; ++k) {
        float d = X[mi][k] - X[l][k];
        s = fmaf(d, d, s);
      }
      pk = ((u64)fkey(s) << 32) | (u64)(0xFFFFFFFFu - (unsigned)mlist[l]);
    }
    #pragma unroll
    for (int off = 1; off < 64; off <<= 1) {
      u64 o = __shfl_xor(pk, off);
      pk = pk > o ? pk : o;
    }
    if (l == 0)
      posIdx[gi] = ((unsigned)(pk >> 32) > 0x80000000u)
                       ? (int)(0xFFFFFFFFu - (unsigned)(pk & 0xFFFFFFFFull))
                       : gi;
  }
}

// 256x256 pair tile (PROVEN structure: FETCH 8.7MB, 0 bank conflicts).
// Staging/compute identical to the 39.9us kernel; epilogue is neg-only lean:
// unmasked min with diagonal exclusion, 8-bit local-j mantissa stuff,
// lg-merge, one atomicMin per (i, j-block).
__global__ __launch_bounds__(512, 2) void k_gemm(const _Float16* __restrict__ Eh,
                                                 const float* __restrict__ normf,
                                                 u64* __restrict__ negPack) {
  __shared__ __align__(1024) _Float16 As[256 * 128];  // j rows, XOR-swizzled
  __shared__ __align__(1024) _Float16 Bs[256 * 128];  // i rows, XOR-swizzled
  __shared__ __align__(16) float njs[256];

  const int t = threadIdx.x;
  const int w = t >> 6, l = t & 63;
  const int jbase = (blockIdx.x >> 5) * 256;
  const int ibase = (blockIdx.x & 31) * 256;
  const int lane15 = l & 15, lg = l >> 4;
  const int iw = w & 3, jw = w >> 2;  // 4 i-waves x 2 j-waves

  // ---- stage 128KB: coalesced global reads, swizzled ds_write ----
  {
    const int cp = lane15 << 4;  // byte col 0..240
    #pragma unroll
    for (int ci = 0; ci < 16; ++ci) {
      int chunk = w * 16 + ci;          // 0..127
      int r = (chunk & 63) * 4 + lg;    // row 0..255
      int gbase = (chunk < 64) ? jbase : ibase;
      _Float16* tile = (chunk < 64) ? As : Bs;
      half8 v = *(const half8*)((const char*)Eh + (size_t)(gbase + r) * 256 + cp);
      *(half8*)((char*)tile + r * 256 + (cp ^ ((r & 7) << 4))) = v;
    }
    if (t < 64) *(float4*)&njs[t * 4] = *(const float4*)&normf[jbase + t * 4];
  }
  __syncthreads();

  // ---- compute: wave-tile 128j x 64i = 8x4 16x16 tiles ----
  f32x4 acc[8][4];
  #pragma unroll
  for (int a = 0; a < 8; ++a)
    #pragma unroll
    for (int b = 0; b < 4; ++b) acc[a][b] = (f32x4){0.f, 0.f, 0.f, 0.f};

  #pragma unroll
  for (int ks = 0; ks < 4; ++ks) {
    const int bc = ks * 64 + lg * 16;  // byte col of this lane's K-slice
    half8 af[8], bf[4];
    #pragma unroll
    for (int jt = 0; jt < 8; ++jt) {
      int r = jw * 128 + jt * 16 + lane15;
      af[jt] = *(const half8*)((const char*)As + r * 256 + (bc ^ ((r & 7) << 4)));
    }
    #pragma unroll
    for (int it = 0; it < 4; ++it) {
      int r = iw * 64 + it * 16 + lane15;
      bf[it] = *(const half8*)((const char*)Bs + r * 256 + (bc ^ ((r & 7) << 4)));
    }
    #pragma unroll
    for (int jt = 0; jt < 8; ++jt)
      #pragma unroll
      for (int it = 0; it < 4; ++it)
        acc[jt][it] = __builtin_amdgcn_mfma_f32_16x16x32_f16(af[jt], bf[it], acc[jt][it], 0, 0, 0);
  }

  // ---- lean neg-only epilogue: d'' = nj - 2g (ni dropped: row-constant),
  // 8-bit block-local j stuffed in mantissa, running fmin ----
  const bool diag = (ibase == jbase);
  float bn[4] = {BIGf, BIGf, BIGf, BIGf};

  #pragma unroll
  for (int jt = 0; jt < 8; ++jt) {
    const int jr0 = jw * 128 + jt * 16 + lg * 4;  // block-local j of reg 0
    const float4 nj4 = *(const float4*)&njs[jr0];
    #pragma unroll
    for (int it = 0; it < 4; ++it) {
      float c0 = fmaf(acc[jt][it][0], -2.0f, nj4.x);
      float c1 = fmaf(acc[jt][it][1], -2.0f, nj4.y);
      float c2 = fmaf(acc[jt][it][2], -2.0f, nj4.z);
      float c3 = fmaf(acc[jt][it][3], -2.0f, nj4.w);
      c0 = __uint_as_float((__float_as_uint(c0) & 0xFFFFFF00u) | (unsigned)(jr0 + 0));
      c1 = __uint_as_float((__float_as_uint(c1) & 0xFFFFFF00u) | (unsigned)(jr0 + 1));
      c2 = __uint_as_float((__float_as_uint(c2) & 0xFFFFFF00u) | (unsigned)(jr0 + 2));
      c3 = __uint_as_float((__float_as_uint(c3) & 0xFFFFFF00u) | (unsigned)(jr0 + 3));
      if (diag) {  // block-uniform branch: exclude j == i
        int dloc = iw * 64 + it * 16 + lane15 - jr0;
        if (dloc == 0) c0 = BIGf;
        else if (dloc == 1) c1 = BIGf;
        else if (dloc == 2) c2 = BIGf;
        else if (dloc == 3) c3 = BIGf;
      }
      bn[it] = fminf(bn[it], fminf(fminf(c0, c1), fminf(c2, c3)));
    }
  }

  // merge the 4 lg-lanes (same i, disjoint j), then one atomic per (i, block)
  #pragma unroll
  for (int it = 0; it < 4; ++it) {
    bn[it] = fminf(bn[it], __shfl_xor(bn[it], 16));
    bn[it] = fminf(bn[it], __shfl_xor(bn[it], 32));
  }
  if (l < 16) {
    #pragma unroll
    for (int it = 0; it < 4; ++it) {
      int gi = ibase + iw * 64 + it * 16 + lane15;
      unsigned gj = (unsigned)jbase + (__float_as_uint(bn[it]) & 255u);
      atomicMin(negPack + gi, ((u64)fkey(bn[it]) << 32) | (u64)gj);
    }
  }
}

// One wave per row: exact fp32 triplet term from the selected indices.
__global__ __launch_bounds__(256) void k_final(const float* __restrict__ E,
                                               const int* __restrict__ posIdx,
                                               const u64* __restrict__ negPack,
                                               float* __restrict__ rowLoss) {
  int i = (blockIdx.x * 256 + threadIdx.x) >> 6;
  int l = threadIdx.x & 63;
  int jn = (int)((unsigned)(negPack[i] & 0xFFFFFFFFull) & 8191u);
  int jp = posIdx[i];
  float2 a = *(const float2*)(E + (size_t)i * Dd + l * 2);
  float2 p = *(const float2*)(E + (size_t)jp * Dd + l * 2);
  float2 n = *(const float2*)(E + (size_t)jn * Dd + l * 2);
  float dx = a.x - p.x + EPSf, dy = a.y - p.y + EPSf;
  float sap = dx * dx + dy * dy;
  dx = a.x - n.x + EPSf;
  dy = a.y - n.y + EPSf;
  float san = dx * dx + dy * dy;
  #pragma unroll
  for (int off = 32; off; off >>= 1) {
    sap += __shfl_xor(sap, off);
    san += __shfl_xor(san, off);
  }
  if (l == 0) rowLoss[i] = fmaxf(sqrtf(sap) - sqrtf(san) + MARGINf, 0.0f);
}

// Deterministic tree reduction -> mean.
__global__ __launch_bounds__(256) void k_reduce(const float* __restrict__ rowLoss,
                                                float* __restrict__ out) {
  __shared__ float s[256];
  int t = threadIdx.x;
  float sum = 0.f;
  for (int q = 0; q < 32; ++q) sum += rowLoss[t + 256 * q];
  s[t] = sum;
  __syncthreads();
  for (int off = 128; off; off >>= 1) {
    if (t < off) s[t] += s[t + off];
    __syncthreads();
  }
  if (t == 0) out[0] = s[0] * (1.0f / 8192.0f);
}

extern "C" void kernel_launch(void* const* d_in, const int* in_sizes, int n_in,
                              void* d_out, int out_size, void* d_ws, size_t ws_size,
                              hipStream_t stream) {
  const float* E = (const float*)d_in[0];
  const int* lab = (const int*)d_in[1];
  float* out = (float*)d_out;

  char* wsp = (char*)d_ws;
  u64* negPack = (u64*)wsp;                        // 64 KB
  int* posIdx = (int*)(wsp + (64 << 10));          // 32 KB
  float* normf = (float*)(wsp + (96 << 10));       // 32 KB
  float* rowLoss = (float*)(wsp + (128 << 10));    // 32 KB
  _Float16* Eh = (_Float16*)(wsp + (192 << 10));   // 2 MB row-major fp16

  k_prep<<<2048, 256, 0, stream>>>(E, Eh, normf, negPack);
  k_pos<<<1000, 256, 0, stream>>>(E, lab, posIdx);
  k_gemm<<<1024, 512, 0, stream>>>(Eh, normf, negPack);
  k_final<<<2048, 256, 0, stream>>>(E, posIdx, negPack, rowLoss);
  k_reduce<<<1, 256, 0, stream>>>(rowLoss, out);
}

// Round 10
// 54.195 us; speedup vs baseline: 2.5460x; 1.3198x over previous
//
#include <hip/hip_runtime.h>
#include <cstdint>

typedef unsigned long long u64;
typedef _Float16 half8 __attribute__((ext_vector_type(8)));
typedef float f32x4 __attribute__((ext_vector_type(4)));

static constexpr int Dd = 128;
static constexpr float EPSf = 1e-6f;
static constexpr float MARGINf = 1.0f;
static constexpr float BIGf = 3.0e38f;

// Monotonic map fp32 -> u32 (total order matching float compare).
__device__ __forceinline__ unsigned fkey(float f) {
  unsigned b = __float_as_uint(f);
  return (b & 0x80000000u) ? ~b : (b | 0x80000000u);
}

// Block = 16 rows. Packed fragment-major fp16:
// half idx = ((T*4+ks)*64 + lg*16 + r15)*8 + h ; T=row>>4, k=ks*32+lg*8+h.
// Also exact fp32 norms and pos/neg pack init.
__global__ __launch_bounds__(256) void k_prep(const float* __restrict__ E,
                                              _Float16* __restrict__ Ehp,
                                              float* __restrict__ normf,
                                              u64* __restrict__ posPack,
                                              u64* __restrict__ negPack) {
  __shared__ float part[4][16];
  const int t = threadIdx.x;
  const int b = blockIdx.x;  // rows [b*16, b*16+16)
  const int ks = t >> 6, r15 = t & 15;
  const int lg = (t >> 4) & 3;
  const float* src = E + (size_t)(b * 16 + r15) * Dd + ks * 32 + lg * 8;
  float4 v0 = *(const float4*)src;
  float4 v1 = *(const float4*)(src + 4);
  half8 hv;
  hv[0] = (_Float16)v0.x; hv[1] = (_Float16)v0.y;
  hv[2] = (_Float16)v0.z; hv[3] = (_Float16)v0.w;
  hv[4] = (_Float16)v1.x; hv[5] = (_Float16)v1.y;
  hv[6] = (_Float16)v1.z; hv[7] = (_Float16)v1.w;
  *(half8*)((char*)Ehp + (size_t)b * 4096 + t * 16) = hv;  // fully coalesced
  float s = v0.x * v0.x + v0.y * v0.y + v0.z * v0.z + v0.w * v0.w +
            v1.x * v1.x + v1.y * v1.y + v1.z * v1.z + v1.w * v1.w;
  s += __shfl_xor(s, 16);
  s += __shfl_xor(s, 32);
  if (((t >> 4) & 3) == 0) part[ks][r15] = s;
  __syncthreads();
  if (t < 16) {
    int row = b * 16 + t;
    normf[row] = part[0][t] + part[1][t] + part[2][t] + part[3][t];
    posPack[row] = 0ull;
    negPack[row] = ~0ull;
  }
}

// 128x128 pair tile, 256 threads, 64KB LDS -> 2 blocks/CU (cross-block
// overlap hides staging). Packed layout: staging = linear 32KB copies
// (coalesced, 0 bank conflicts); frag ds_read_b128 at l*16 (0 conflicts).
// Fused masked pos/neg arg-reduce epilogue (no k_pos kernel).
__global__ __launch_bounds__(256, 2) void k_gemm(const _Float16* __restrict__ Ehp,
                                                 const float* __restrict__ normf,
                                                 const int* __restrict__ lab,
                                                 u64* __restrict__ posPack,
                                                 u64* __restrict__ negPack) {
  __shared__ __align__(16) char As[32768];  // j rows (packed-linear)
  __shared__ __align__(16) char Bs[32768];  // i rows (packed-linear)
  __shared__ __align__(16) float njs[128];
  __shared__ __align__(16) int ljs[128];

  const int t = threadIdx.x;
  const int w = t >> 6, l = t & 63;
  const int lane15 = l & 15, lg = l >> 4;
  const int iw = w & 1, jw = w >> 1;  // 2 i-waves x 2 j-waves
  const int ibase = (blockIdx.x & 63) * 128;
  const int jbase = (blockIdx.x >> 6) * 128;
  const char* jsrc = (const char*)Ehp + (size_t)(jbase >> 4) * 4096;
  const char* isrc = (const char*)Ehp + (size_t)(ibase >> 4) * 4096;

  // ---- stage 64KB: pure linear packed copies ----
  #pragma unroll
  for (int p = 0; p < 8; ++p)
    *(half8*)(As + p * 4096 + t * 16) = *(const half8*)(jsrc + p * 4096 + t * 16);
  #pragma unroll
  for (int p = 0; p < 8; ++p)
    *(half8*)(Bs + p * 4096 + t * 16) = *(const half8*)(isrc + p * 4096 + t * 16);
  if (t < 128) {
    njs[t] = normf[jbase + t];
    ljs[t] = lab[jbase + t];
  }
  // i-side labels direct (tiny, L2-hot); overlaps staging drain
  int li[4];
  #pragma unroll
  for (int it = 0; it < 4; ++it) li[it] = lab[ibase + iw * 64 + it * 16 + lane15];
  __syncthreads();

  // ---- compute: wave-tile 64j x 64i = 4x4 16x16 tiles ----
  f32x4 acc[4][4];
  #pragma unroll
  for (int a = 0; a < 4; ++a)
    #pragma unroll
    for (int b = 0; b < 4; ++b) acc[a][b] = (f32x4){0.f, 0.f, 0.f, 0.f};

  #pragma unroll
  for (int ks = 0; ks < 4; ++ks) {
    half8 af[4], bf[4];
    #pragma unroll
    for (int jt = 0; jt < 4; ++jt)
      af[jt] = *(const half8*)(As + ((jw * 4 + jt) * 4 + ks) * 1024 + l * 16);
    #pragma unroll
    for (int it = 0; it < 4; ++it)
      bf[it] = *(const half8*)(Bs + ((iw * 4 + it) * 4 + ks) * 1024 + l * 16);
    __builtin_amdgcn_s_setprio(1);
    #pragma unroll
    for (int jt = 0; jt < 4; ++jt)
      #pragma unroll
      for (int it = 0; it < 4; ++it)
        acc[jt][it] = __builtin_amdgcn_mfma_f32_16x16x32_f16(af[jt], bf[it], acc[jt][it], 0, 0, 0);
    __builtin_amdgcn_s_setprio(0);
  }

  // ---- fused epilogue: d'' = nj - 2g (ni dropped: row-constant),
  // 7-bit block-local j stuffed in mantissa, masked pos-max / neg-min ----
  float bp[4] = {-BIGf, -BIGf, -BIGf, -BIGf};
  float bn[4] = {BIGf, BIGf, BIGf, BIGf};

  #pragma unroll
  for (int jt = 0; jt < 4; ++jt) {
    const int jr0 = jw * 64 + jt * 16 + lg * 4;  // block-local j of reg 0
    const float4 nj4 = *(const float4*)&njs[jr0];
    const int4 lj4 = *(const int4*)&ljs[jr0];
    #pragma unroll
    for (int it = 0; it < 4; ++it) {
      float c0 = fmaf(acc[jt][it][0], -2.0f, nj4.x);
      float c1 = fmaf(acc[jt][it][1], -2.0f, nj4.y);
      float c2 = fmaf(acc[jt][it][2], -2.0f, nj4.z);
      float c3 = fmaf(acc[jt][it][3], -2.0f, nj4.w);
      c0 = __uint_as_float((__float_as_uint(c0) & 0xFFFFFF80u) | (unsigned)(jr0 + 0));
      c1 = __uint_as_float((__float_as_uint(c1) & 0xFFFFFF80u) | (unsigned)(jr0 + 1));
      c2 = __uint_as_float((__float_as_uint(c2) & 0xFFFFFF80u) | (unsigned)(jr0 + 2));
      c3 = __uint_as_float((__float_as_uint(c3) & 0xFFFFFF80u) | (unsigned)(jr0 + 3));
      bool s0 = (lj4.x == li[it]), s1 = (lj4.y == li[it]);
      bool s2 = (lj4.z == li[it]), s3 = (lj4.w == li[it]);
      float p0 = s0 ? c0 : -BIGf, p1 = s1 ? c1 : -BIGf;
      float p2 = s2 ? c2 : -BIGf, p3 = s3 ? c3 : -BIGf;
      float n0 = s0 ? BIGf : c0, n1 = s1 ? BIGf : c1;
      float n2 = s2 ? BIGf : c2, n3 = s3 ? BIGf : c3;
      bp[it] = fmaxf(bp[it], fmaxf(fmaxf(p0, p1), fmaxf(p2, p3)));
      bn[it] = fminf(bn[it], fminf(fminf(n0, n1), fminf(n2, n3)));
    }
  }

  // merge the 4 lg-lanes (same i, disjoint j), then atomics (one per i,block)
  #pragma unroll
  for (int it = 0; it < 4; ++it) {
    bp[it] = fmaxf(bp[it], __shfl_xor(bp[it], 16));
    bp[it] = fmaxf(bp[it], __shfl_xor(bp[it], 32));
    bn[it] = fminf(bn[it], __shfl_xor(bn[it], 16));
    bn[it] = fminf(bn[it], __shfl_xor(bn[it], 32));
  }
  if (l < 16) {
    #pragma unroll
    for (int it = 0; it < 4; ++it) {
      int gi = ibase + iw * 64 + it * 16 + lane15;
      unsigned gjp = (unsigned)jbase + (__float_as_uint(bp[it]) & 127u);
      unsigned gjn = (unsigned)jbase + (__float_as_uint(bn[it]) & 127u);
      atomicMax(posPack + gi, ((u64)fkey(bp[it]) << 32) | (u64)(0xFFFFFFFFu - gjp));
      atomicMin(negPack + gi, ((u64)fkey(bn[it]) << 32) | (u64)gjn);
    }
  }
}

// One wave per row: exact fp32 triplet term from the selected indices.
__global__ __launch_bounds__(256) void k_final(const float* __restrict__ E,
                                               const u64* __restrict__ posPack,
                                               const u64* __restrict__ negPack,
                                               float* __restrict__ rowLoss) {
  int i = (blockIdx.x * 256 + threadIdx.x) >> 6;
  int l = threadIdx.x & 63;
  int jp = (int)(0xFFFFFFFFu - (unsigned)(posPack[i] & 0xFFFFFFFFull));
  int jn = (int)(unsigned)(negPack[i] & 0xFFFFFFFFull);
  float2 a = *(const float2*)(E + (size_t)i * Dd + l * 2);
  float2 p = *(const float2*)(E + (size_t)jp * Dd + l * 2);
  float2 n = *(const float2*)(E + (size_t)jn * Dd + l * 2);
  float dx = a.x - p.x + EPSf, dy = a.y - p.y + EPSf;
  float sap = dx * dx + dy * dy;
  dx = a.x - n.x + EPSf;
  dy = a.y - n.y + EPSf;
  float san = dx * dx + dy * dy;
  #pragma unroll
  for (int off = 32; off; off >>= 1) {
    sap += __shfl_xor(sap, off);
    san += __shfl_xor(san, off);
  }
  if (l == 0) rowLoss[i] = fmaxf(sqrtf(sap) - sqrtf(san) + MARGINf, 0.0f);
}

// Deterministic tree reduction -> mean.
__global__ __launch_bounds__(256) void k_reduce(const float* __restrict__ rowLoss,
                                                float* __restrict__ out) {
  __shared__ float s[256];
  int t = threadIdx.x;
  float sum = 0.f;
  for (int q = 0; q < 32; ++q) sum += rowLoss[t + 256 * q];
  s[t] = sum;
  __syncthreads();
  for (int off = 128; off; off >>= 1) {
    if (t < off) s[t] += s[t + off];
    __syncthreads();
  }
  if (t == 0) out[0] = s[0] * (1.0f / 8192.0f);
}

extern "C" void kernel_launch(void* const* d_in, const int* in_sizes, int n_in,
                              void* d_out, int out_size, void* d_ws, size_t ws_size,
                              hipStream_t stream) {
  const float* E = (const float*)d_in[0];
  const int* lab = (const int*)d_in[1];
  float* out = (float*)d_out;

  char* wsp = (char*)d_ws;
  u64* posPack = (u64*)wsp;                        // 64 KB
  u64* negPack = (u64*)(wsp + (64 << 10));         // 64 KB
  float* normf = (float*)(wsp + (128 << 10));      // 32 KB
  float* rowLoss = (float*)(wsp + (160 << 10));    // 32 KB
  _Float16* Ehp = (_Float16*)(wsp + (192 << 10));  // 2 MB packed frags

  k_prep<<<512, 256, 0, stream>>>(E, Ehp, normf, posPack, negPack);
  k_gemm<<<4096, 256, 0, stream>>>(Ehp, normf, lab, posPack, negPack);
  k_final<<<2048, 256, 0, stream>>>(E, posPack, negPack, rowLoss);
  k_reduce<<<1, 256, 0, stream>>>(rowLoss, out);
}

// Round 11
// 46.020 us; speedup vs baseline: 2.9982x; 1.1776x over previous
//
#include <hip/hip_runtime.h>
#include <cstdint>

typedef unsigned long long u64;
typedef _Float16 half8 __attribute__((ext_vector_type(8)));
typedef float f32x4 __attribute__((ext_vector_type(4)));

static constexpr int Dd = 128;
static constexpr float EPSf = 1e-6f;
static constexpr float MARGINf = 1.0f;
static constexpr float BIGf = 3.0e38f;

// Monotonic map fp32 -> u32 (total order matching float compare).
__device__ __forceinline__ unsigned fkey(float f) {
  unsigned b = __float_as_uint(f);
  return (b & 0x80000000u) ? ~b : (b | 0x80000000u);
}

// Block = 16 rows. Packed fragment-major fp16:
// half idx = ((T*4+ks)*64 + lg*16 + r15)*8 + h ; T=row>>4, k=ks*32+lg*8+h.
__global__ __launch_bounds__(256) void k_prep(const float* __restrict__ E,
                                              _Float16* __restrict__ Ehp,
                                              float* __restrict__ normf) {
  __shared__ float part[4][16];
  const int t = threadIdx.x;
  const int b = blockIdx.x;  // rows [b*16, b*16+16)
  const int ks = t >> 6, r15 = t & 15;
  const int lg = (t >> 4) & 3;
  const float* src = E + (size_t)(b * 16 + r15) * Dd + ks * 32 + lg * 8;
  float4 v0 = *(const float4*)src;
  float4 v1 = *(const float4*)(src + 4);
  half8 hv;
  hv[0] = (_Float16)v0.x; hv[1] = (_Float16)v0.y;
  hv[2] = (_Float16)v0.z; hv[3] = (_Float16)v0.w;
  hv[4] = (_Float16)v1.x; hv[5] = (_Float16)v1.y;
  hv[6] = (_Float16)v1.z; hv[7] = (_Float16)v1.w;
  *(half8*)((char*)Ehp + (size_t)b * 4096 + t * 16) = hv;  // fully coalesced
  float s = v0.x * v0.x + v0.y * v0.y + v0.z * v0.z + v0.w * v0.w +
            v1.x * v1.x + v1.y * v1.y + v1.z * v1.z + v1.w * v1.w;
  s += __shfl_xor(s, 16);
  s += __shfl_xor(s, 32);
  if (((t >> 4) & 3) == 0) part[ks][r15] = s;
  __syncthreads();
  if (t < 16) normf[b * 16 + t] = part[0][t] + part[1][t] + part[2][t] + part[3][t];
}

// Streamer: block = 128 i-rows (i-panel in LDS, staged once) x 1024 j-rows
// (16 double-buffered 16KB tiles). T14 split: next-tile loads -> regs before
// compute, ds_write after barrier. No atomics: per-(strip,jw) partial stores.
__global__ __launch_bounds__(256, 4) void k_gemm(const _Float16* __restrict__ Ehp,
                                                 const float* __restrict__ normf,
                                                 const int* __restrict__ lab,
                                                 u64* __restrict__ posPart,
                                                 u64* __restrict__ negPart) {
  __shared__ __align__(16) char As[32768];     // i-panel, packed-linear
  __shared__ __align__(16) char Jb[2][16384];  // j dbuf, 64 rows each
  __shared__ __align__(16) float njs[1024];
  __shared__ __align__(16) int ljs[1024];

  const int t = threadIdx.x;
  const int w = t >> 6, l = t & 63;
  const int lane15 = l & 15, lg = l >> 4;
  const int iw = w & 1, jw = w >> 1;     // 2 i-groups x 2 j-groups
  const int panel = blockIdx.x;          // 64 i-panels
  const int strip = blockIdx.y;          // 8 j-strips
  const int ibase = panel * 128;
  const int jbase = strip * 1024;
  const char* isrc = (const char*)Ehp + (size_t)(ibase >> 4) * 4096;
  const char* jsrc = (const char*)Ehp + (size_t)(jbase >> 4) * 4096;

  // ---- prologue: i-panel 32KB + strip norms/labels 8KB + j-tile0 16KB ----
  #pragma unroll
  for (int q = 0; q < 8; ++q)
    *(half8*)(As + q * 4096 + t * 16) = *(const half8*)(isrc + q * 4096 + t * 16);
  *(float4*)&njs[t * 4] = *(const float4*)&normf[jbase + t * 4];
  *(int4*)&ljs[t * 4] = *(const int4*)&lab[jbase + t * 4];
  #pragma unroll
  for (int q = 0; q < 4; ++q)
    *(half8*)(Jb[0] + q * 4096 + t * 16) = *(const half8*)(jsrc + q * 4096 + t * 16);

  int li[4];
  #pragma unroll
  for (int it = 0; it < 4; ++it) li[it] = lab[ibase + iw * 64 + it * 16 + lane15];
  __syncthreads();

  float bp[4] = {-BIGf, -BIGf, -BIGf, -BIGf};
  float bn[4] = {BIGf, BIGf, BIGf, BIGf};

  for (int tile = 0; tile < 16; ++tile) {
    const int cur = tile & 1;
    // T14: issue next tile's global loads now; latency hides under compute
    half8 sreg[4];
    if (tile < 15) {
      const char* s = jsrc + (size_t)(tile + 1) * 16384;
      #pragma unroll
      for (int q = 0; q < 4; ++q) sreg[q] = *(const half8*)(s + q * 4096 + t * 16);
    }

    // ---- compute: wave-tile 64i x 32j on Jb[cur] ----
    f32x4 acc[2][4];
    #pragma unroll
    for (int a = 0; a < 2; ++a)
      #pragma unroll
      for (int b = 0; b < 4; ++b) acc[a][b] = (f32x4){0.f, 0.f, 0.f, 0.f};

    #pragma unroll
    for (int ks = 0; ks < 4; ++ks) {
      half8 aj[2], bi[4];
      #pragma unroll
      for (int jt = 0; jt < 2; ++jt)
        aj[jt] = *(const half8*)(Jb[cur] + ((jw * 2 + jt) * 4 + ks) * 1024 + l * 16);
      #pragma unroll
      for (int it = 0; it < 4; ++it)
        bi[it] = *(const half8*)(As + ((iw * 4 + it) * 4 + ks) * 1024 + l * 16);
      __builtin_amdgcn_s_setprio(1);
      #pragma unroll
      for (int jt = 0; jt < 2; ++jt)
        #pragma unroll
        for (int it = 0; it < 4; ++it)
          acc[jt][it] = __builtin_amdgcn_mfma_f32_16x16x32_f16(aj[jt], bi[it], acc[jt][it], 0, 0, 0);
      __builtin_amdgcn_s_setprio(0);
    }

    // ---- epilogue: d'' = nj - 2g, 10-bit strip-local j stuffed in mantissa,
    // masked pos-max / neg-min (identical semantics to validated rounds) ----
    #pragma unroll
    for (int jt = 0; jt < 2; ++jt) {
      const int jr0 = tile * 64 + jw * 32 + jt * 16 + lg * 4;  // strip-local
      const float4 nj4 = *(const float4*)&njs[jr0];
      const int4 lj4 = *(const int4*)&ljs[jr0];
      #pragma unroll
      for (int it = 0; it < 4; ++it) {
        float c0 = fmaf(acc[jt][it][0], -2.0f, nj4.x);
        float c1 = fmaf(acc[jt][it][1], -2.0f, nj4.y);
        float c2 = fmaf(acc[jt][it][2], -2.0f, nj4.z);
        float c3 = fmaf(acc[jt][it][3], -2.0f, nj4.w);
        c0 = __uint_as_float((__float_as_uint(c0) & 0xFFFFFC00u) | (unsigned)(jr0 + 0));
        c1 = __uint_as_float((__float_as_uint(c1) & 0xFFFFFC00u) | (unsigned)(jr0 + 1));
        c2 = __uint_as_float((__float_as_uint(c2) & 0xFFFFFC00u) | (unsigned)(jr0 + 2));
        c3 = __uint_as_float((__float_as_uint(c3) & 0xFFFFFC00u) | (unsigned)(jr0 + 3));
        bool s0 = (lj4.x == li[it]), s1 = (lj4.y == li[it]);
        bool s2 = (lj4.z == li[it]), s3 = (lj4.w == li[it]);
        float p0 = s0 ? c0 : -BIGf, p1 = s1 ? c1 : -BIGf;
        float p2 = s2 ? c2 : -BIGf, p3 = s3 ? c3 : -BIGf;
        float n0 = s0 ? BIGf : c0, n1 = s1 ? BIGf : c1;
        float n2 = s2 ? BIGf : c2, n3 = s3 ? BIGf : c3;
        bp[it] = fmaxf(bp[it], fmaxf(fmaxf(p0, p1), fmaxf(p2, p3)));
        bn[it] = fminf(bn[it], fminf(fminf(n0, n1), fminf(n2, n3)));
      }
    }

    __syncthreads();  // all waves done reading Jb[cur]
    if (tile < 15) {
      #pragma unroll
      for (int q = 0; q < 4; ++q)
        *(half8*)(Jb[cur ^ 1] + q * 4096 + t * 16) = sreg[q];
    }
    __syncthreads();  // next tile visible
  }

  // merge the 4 lg-lanes (same i, disjoint j), plain partial stores
  #pragma unroll
  for (int it = 0; it < 4; ++it) {
    bp[it] = fmaxf(bp[it], __shfl_xor(bp[it], 16));
    bp[it] = fmaxf(bp[it], __shfl_xor(bp[it], 32));
    bn[it] = fminf(bn[it], __shfl_xor(bn[it], 16));
    bn[it] = fminf(bn[it], __shfl_xor(bn[it], 32));
  }
  if (l < 16) {
    const int slot = strip * 2 + jw;
    #pragma unroll
    for (int it = 0; it < 4; ++it) {
      int gi = ibase + iw * 64 + it * 16 + lane15;
      unsigned gjp = (unsigned)jbase + (__float_as_uint(bp[it]) & 1023u);
      unsigned gjn = (unsigned)jbase + (__float_as_uint(bn[it]) & 1023u);
      posPart[(size_t)slot * 8192 + gi] =
          ((u64)fkey(bp[it]) << 32) | (u64)(0xFFFFFFFFu - gjp);
      negPart[(size_t)slot * 8192 + gi] = ((u64)fkey(bn[it]) << 32) | (u64)gjn;
    }
  }
}

// One wave per row: merge 16 partial slots, exact fp32 triplet term.
__global__ __launch_bounds__(256) void k_final(const float* __restrict__ E,
                                               const u64* __restrict__ posPart,
                                               const u64* __restrict__ negPart,
                                               float* __restrict__ rowLoss) {
  int i = (blockIdx.x * 256 + threadIdx.x) >> 6;
  int l = threadIdx.x & 63;
  u64 pp = 0ull, np = ~0ull;
  if (l < 16) {
    pp = posPart[(size_t)l * 8192 + i];
    np = negPart[(size_t)l * 8192 + i];
  }
  #pragma unroll
  for (int off = 1; off < 64; off <<= 1) {
    u64 a = __shfl_xor(pp, off);
    u64 b = __shfl_xor(np, off);
    pp = pp > a ? pp : a;
    np = np < b ? np : b;
  }
  int jp = (int)((0xFFFFFFFFu - (unsigned)(pp & 0xFFFFFFFFull)) & 8191u);
  int jn = (int)((unsigned)(np & 0xFFFFFFFFull) & 8191u);
  float2 a = *(const float2*)(E + (size_t)i * Dd + l * 2);
  float2 p = *(const float2*)(E + (size_t)jp * Dd + l * 2);
  float2 n = *(const float2*)(E + (size_t)jn * Dd + l * 2);
  float dx = a.x - p.x + EPSf, dy = a.y - p.y + EPSf;
  float sap = dx * dx + dy * dy;
  dx = a.x - n.x + EPSf;
  dy = a.y - n.y + EPSf;
  float san = dx * dx + dy * dy;
  #pragma unroll
  for (int off = 32; off; off >>= 1) {
    sap += __shfl_xor(sap, off);
    san += __shfl_xor(san, off);
  }
  if (l == 0) rowLoss[i] = fmaxf(sqrtf(sap) - sqrtf(san) + MARGINf, 0.0f);
}

// Deterministic tree reduction -> mean.
__global__ __launch_bounds__(256) void k_reduce(const float* __restrict__ rowLoss,
                                                float* __restrict__ out) {
  __shared__ float s[256];
  int t = threadIdx.x;
  float sum = 0.f;
  for (int q = 0; q < 32; ++q) sum += rowLoss[t + 256 * q];
  s[t] = sum;
  __syncthreads();
  for (int off = 128; off; off >>= 1) {
    if (t < off) s[t] += s[t + off];
    __syncthreads();
  }
  if (t == 0) out[0] = s[0] * (1.0f / 8192.0f);
}

extern "C" void kernel_launch(void* const* d_in, const int* in_sizes, int n_in,
                              void* d_out, int out_size, void* d_ws, size_t ws_size,
                              hipStream_t stream) {
  const float* E = (const float*)d_in[0];
  const int* lab = (const int*)d_in[1];
  float* out = (float*)d_out;

  char* wsp = (char*)d_ws;
  u64* posPart = (u64*)wsp;                         // 16*8192*8 = 1 MB
  u64* negPart = (u64*)(wsp + (1024 << 10));        // 1 MB
  float* normf = (float*)(wsp + (2048 << 10));      // 32 KB
  float* rowLoss = (float*)(wsp + (2080 << 10));    // 32 KB
  _Float16* Ehp = (_Float16*)(wsp + (2112 << 10));  // 2 MB packed frags

  k_prep<<<512, 256, 0, stream>>>(E, Ehp, normf);
  k_gemm<<<dim3(64, 8), 256, 0, stream>>>(Ehp, normf, lab, posPart, negPart);
  k_final<<<2048, 256, 0, stream>>>(E, posPart, negPart, rowLoss);
  k_reduce<<<1, 256, 0, stream>>>(rowLoss, out);
}